// Round 5
// baseline (482.933 us; speedup 1.0000x reference)
//
#include <hip/hip_runtime.h>
#include <hip/hip_bf16.h>

#define LFULL 8192
#define HDIM 1024
#define KPAD 8448  // 66 chunks of 128 elems (last 2 chunks zeros)

typedef __attribute__((ext_vector_type(8))) short bf16x8;
typedef __attribute__((ext_vector_type(4))) float f32x4;
typedef __attribute__((ext_vector_type(16))) float f32x16;

union U16 {
  uint4 u;
  bf16x8 s;
  ushort e[8];
};

__device__ __forceinline__ ushort f2bf(float x) {
  union { float f; uint u; } a;
  a.f = x;
  uint r = a.u + 0x7fffu + ((a.u >> 16) & 1u);
  return (ushort)(r >> 16);
}
__device__ __forceinline__ float bf2f(ushort x) {
  union { uint u; float f; } a;
  a.u = ((uint)x) << 16;
  return a.f;
}

__device__ __forceinline__ void gload16(const void* src, void* lds) {
  __builtin_amdgcn_global_load_lds(
      (const __attribute__((address_space(1))) unsigned int*)src,
      (__attribute__((address_space(3))) unsigned int*)lds, 16, 0, 0);
}

__device__ __forceinline__ uint ALIGNB(uint hi, uint lo, uint sh) {
#if __has_builtin(__builtin_amdgcn_alignbyte)
  return __builtin_amdgcn_alignbyte(hi, lo, sh);
#else
  return (uint)((((unsigned long long)hi << 32) | (unsigned long long)lo) >> (8u * sh));
#endif
}

// 4-bit XOR swizzle for Us 16B-chunk index (bijective: low4 ^= bits7:4)
#define USWZ16(cI) ((cI) ^ (((cI) >> 4) & 15))

// ---------------------------------------------------------------------------
// Kernel 1: multi-scale kernel synthesis + L2 norm -> bf16 kbrev[h][8448]
// kbrev[h][x] = k_norm[h][8191-x], zeros for x >= 8192.
// ---------------------------------------------------------------------------
__global__ __launch_bounds__(256) void k_synth_kernel(
    const float* __restrict__ kern, ushort* __restrict__ kout) {
  const int h = blockIdx.x;
  const int tid = threadIdx.x;
  __shared__ float Kw[8][64];
  __shared__ __align__(16) float kv[LFULL];
  __shared__ float red[8];
  for (int idx = tid; idx < 8 * 64; idx += 256) {
    int i = idx >> 6, j = idx & 63;
    Kw[i][j] = kern[(i * HDIM + h) * 64 + j];
  }
  __syncthreads();
  const float mult = (float)(1.0 + 3.0 * (double)h / 1023.0);
  float pw[8];
  pw[7] = 1.0f;
#pragma unroll
  for (int i = 6; i >= 0; --i) pw[i] = pw[i + 1] * mult;
  float ss = 0.0f;
  for (int m = tid; m < LFULL; m += 256) {
    const int i = (m < 64) ? 0 : (32 - __clz(m >> 6));
    const int slog = (i == 0) ? 0 : (i - 1);
    const float inv_s = 1.0f / (float)(1 << slog);
    const int off = (i == 0) ? 0 : (64 << (i - 1));
    const int t = m - off;
    const float pos = ((float)t + 0.5f) * inv_s - 0.5f;
    const float lof = floorf(pos);
    const float wgt = pos - lof;
    int lo = (int)lof;
    int hi = lo + 1;
    lo = min(63, max(0, lo));
    hi = min(63, max(0, hi));
    const float val = (Kw[i][lo] * (1.0f - wgt) + Kw[i][hi] * wgt) * pw[i];
    kv[m] = val;
    ss += val * val;
  }
#pragma unroll
  for (int o = 32; o > 0; o >>= 1) ss += __shfl_xor(ss, o, 64);
  if ((tid & 63) == 0) red[tid >> 6] = ss;
  __syncthreads();
  if (tid == 0) red[0] = sqrtf(red[0] + red[1] + red[2] + red[3]);
  __syncthreads();
  const float inv_norm = 1.0f / red[0];
  ushort* krow = kout + (size_t)h * KPAD;
  for (int m = tid; m < LFULL; m += 256) krow[8191 - m] = f2bf(kv[m] * inv_norm);
  if (tid < 256) krow[8192 + tid] = 0;
}

// ---------------------------------------------------------------------------
// Kernel 2: causal conv via block-Toeplitz 32x32x16 MFMA, T=128 blocks.
// Block = 1 h, 4 waves (one per b). Per step d (0..63): Y_i += K_d*U_{i-d},
// i = 32f + c32 (f=0,1). A = 14 k-windows (8 fresh via 3x ds_read_b64 +
// lane-const select/alignbyte, 6 carried in regs via W(d+1)[mm]=W(d)[mm+8]).
// B = u-frags from XOR16-swizzled Us, 4x rg-reuse. kbrev streamed through a
// per-wave 8-slot LDS ring (reg-staged). No barriers in the main loop.
// ---------------------------------------------------------------------------
__global__ __launch_bounds__(256, 2) void conv_mfma_kernel(
    const float* __restrict__ u, const ushort* __restrict__ kbrev,
    const float* __restrict__ Dp, ushort* __restrict__ g) {
  __shared__ __align__(16) ushort Us[4 * LFULL];   // 64 KB
  __shared__ __align__(16) ushort Ring[4][1152];   // 9 KB: 8 slots + dup
  const int tid = threadIdx.x;
  const int h = blockIdx.x;
  const int w = tid >> 6;  // wave index == b
  const int lane = tid & 63;
  const int c32 = lane & 31;
  const int qh = lane >> 5;
  uint4* Us4 = (uint4*)Us;

  // ---- stage u: fp32 -> bf16, XOR16-swizzled 16B chunks ----
  for (int cc = tid; cc < 4096; cc += 256) {
    const int row = cc >> 10, cI = cc & 1023;
    const float* up = u + (((size_t)(row * HDIM + h)) << 13) + (cI << 3);
    const float4 v0 = *(const float4*)up;
    const float4 v1 = *(const float4*)(up + 4);
    U16 pk;
    pk.e[0] = f2bf(v0.x); pk.e[1] = f2bf(v0.y);
    pk.e[2] = f2bf(v0.z); pk.e[3] = f2bf(v0.w);
    pk.e[4] = f2bf(v1.x); pk.e[5] = f2bf(v1.y);
    pk.e[6] = f2bf(v1.z); pk.e[7] = f2bf(v1.w);
    Us4[(row << 10) + USWZ16(cI)] = pk.u;
  }

  // ---- ring prologue: chunks 65,64(+dup),63 staged via regs; 62 in kreg ----
  const ushort* kr = kbrev + (size_t)h * KPAD;
  char* ringb = (char*)Ring[w];
  {
    const uint kc65 = *(const uint*)(kr + 65 * 128 + 2 * lane);
    const uint kc64 = *(const uint*)(kr + 64 * 128 + 2 * lane);
    const uint kc63 = *(const uint*)(kr + 63 * 128 + 2 * lane);
    *(uint*)(ringb + 1 * 256 + 4 * lane) = kc65;
    *(uint*)(ringb + 0 * 256 + 4 * lane) = kc64;
    *(uint*)(ringb + 2048 + 4 * lane) = kc64;  // dup of slot 0
    *(uint*)(ringb + 7 * 256 + 4 * lane) = kc63;
  }
  uint kreg = *(const uint*)(kr + 62 * 128 + 2 * lane);
  __syncthreads();

  f32x16 acc[2][4];
#pragma unroll
  for (int f = 0; f < 2; ++f)
#pragma unroll
    for (int rg = 0; rg < 4; ++rg)
#pragma unroll
      for (int q = 0; q < 16; ++q) acc[f][rg][q] = 0.0f;

  const int PBASE = 8191 - c32 + 8 * qh;  // P = PBASE + 128 - 128d - 16mm
  const bool s8 = ((PBASE >> 1) & 1) != 0;
  const uint sh = 2u * (uint)(PBASE & 1);

  uint4 WA[15], WB[15];

#define BUILD_W(DD, MM, DST) {                                          \
    const int P = PBASE + 128 - 128 * (DD) - 16 * (MM);                 \
    const int LL = (2 * (P & 1023)) & ~7;                               \
    const uint2 r0 = *(const uint2*)(ringb + LL);                       \
    const uint2 r1 = *(const uint2*)(ringb + LL + 8);                   \
    const uint2 r2 = *(const uint2*)(ringb + LL + 16);                  \
    const uint v0 = s8 ? r0.y : r0.x;                                   \
    const uint v1 = s8 ? r1.x : r0.y;                                   \
    const uint v2 = s8 ? r1.y : r1.x;                                   \
    const uint v3 = s8 ? r2.x : r1.y;                                   \
    const uint v4 = s8 ? r2.y : r2.x;                                   \
    (DST).x = ALIGNB(v1, v0, sh);                                       \
    (DST).y = ALIGNB(v2, v1, sh);                                       \
    (DST).z = ALIGNB(v3, v2, sh);                                       \
    (DST).w = ALIGNB(v4, v3, sh); }

#define WGET(Wc, Wf, MM) ((MM) >= 7 ? (Wf)[(MM)] : (Wc)[(MM) + 8])

#define FPART(DD, F, DIAG, Wc, Wf) {                                    \
    const int j0 = (F) * 32 + c32 - (DD);                               \
    const int jc = j0 < 0 ? 0 : j0;                                     \
    const uint zmask = ((DIAG) && (j0 < 0)) ? 0u : 0xffffffffu;         \
    _Pragma("unroll")                                                   \
    for (int ks = 0; ks < 8; ++ks) {                                    \
      const int cI = 16 * jc + 2 * ks + qh;                             \
      U16 bb;                                                           \
      bb.u = Us4[(w << 10) + USWZ16(cI)];                               \
      if (DIAG) {                                                       \
        bb.u.x &= zmask; bb.u.y &= zmask;                               \
        bb.u.z &= zmask; bb.u.w &= zmask;                               \
      }                                                                 \
      U16 a0, a1, a2, a3;                                               \
      a0.u = WGET(Wc, Wf, 8 - ks);                                      \
      a1.u = WGET(Wc, Wf, 10 - ks);                                     \
      a2.u = WGET(Wc, Wf, 12 - ks);                                     \
      a3.u = WGET(Wc, Wf, 14 - ks);                                     \
      acc[F][0] = __builtin_amdgcn_mfma_f32_32x32x16_bf16(a0.s, bb.s, acc[F][0], 0, 0, 0); \
      acc[F][1] = __builtin_amdgcn_mfma_f32_32x32x16_bf16(a1.s, bb.s, acc[F][1], 0, 0, 0); \
      acc[F][2] = __builtin_amdgcn_mfma_f32_32x32x16_bf16(a2.s, bb.s, acc[F][2], 0, 0, 0); \
      acc[F][3] = __builtin_amdgcn_mfma_f32_32x32x16_bf16(a3.s, bb.s, acc[F][3], 0, 0, 0); \
    } }

#define CONV_STEP(DD, Wc, Wf, HASF0) {                                  \
    _Pragma("unroll")                                                   \
    for (int mm = 7; mm <= 14; ++mm) BUILD_W(DD, mm, (Wf)[mm]);         \
    {                                                                   \
      const int cw0 = 62 - (DD);                                        \
      const int cw = cw0 < 0 ? 0 : cw0;                                 \
      const int sl = (cw & 7) * 256;                                    \
      *(uint*)(ringb + sl + 4 * lane) = kreg;                           \
      *(uint*)(ringb + ((sl == 0) ? 2048 : sl) + 4 * lane) = kreg;      \
      const int cn0 = 61 - (DD);                                        \
      const int cn = cn0 < 0 ? 0 : cn0;                                 \
      kreg = *(const uint*)(kr + cn * 128 + 2 * lane);                  \
    }                                                                   \
    if (HASF0) {                                                        \
      FPART(DD, 0, true, Wc, Wf);                                       \
      FPART(DD, 1, false, Wc, Wf);                                      \
    } else {                                                            \
      FPART(DD, 1, true, Wc, Wf);                                       \
    } }

  // prologue: carried windows for d=0 -> WB[9..14]
#pragma unroll
  for (int mm = 1; mm <= 6; ++mm) BUILD_W(0, mm, WB[mm + 8]);

  for (int dd = 0; dd < 32; dd += 2) {
    CONV_STEP(dd, WB, WA, true);
    CONV_STEP(dd + 1, WA, WB, true);
  }
  for (int dd = 32; dd < 64; dd += 2) {
    CONV_STEP(dd, WB, WA, false);
    CONV_STEP(dd + 1, WA, WB, false);
  }

  // ---- epilogue: += D*u, exact GELU, bf16 store ----
  const float Dh = Dp[h];
  ushort* gp = g + (((size_t)(w * HDIM + h)) << 13);
#pragma unroll
  for (int f = 0; f < 2; ++f) {
#pragma unroll
    for (int rg = 0; rg < 4; ++rg) {
      const int lbase = (f * 32 + c32) * 128 + rg * 32 + 4 * qh;
#pragma unroll
      for (int rq = 0; rq < 4; ++rq) {
        const int l = lbase + 8 * rq;
        const int cI = l >> 3;
        const int phys = USWZ16(cI);
        const uint2 uv = *(const uint2*)(Us + (w << 13) + (phys << 3) + 4 * qh);
        float uu[4];
        uu[0] = bf2f((ushort)(uv.x & 0xffff));
        uu[1] = bf2f((ushort)(uv.x >> 16));
        uu[2] = bf2f((ushort)(uv.y & 0xffff));
        uu[3] = bf2f((ushort)(uv.y >> 16));
        ushort o[4];
#pragma unroll
        for (int jj = 0; jj < 4; ++jj) {
          const float y = acc[f][rg][rq * 4 + jj] + Dh * uu[jj];
          const float ge = 0.5f * y * (1.0f + erff(y * 0.70710678118654752f));
          o[jj] = f2bf(ge);
        }
        uint2 op;
        op.x = (uint)o[0] | ((uint)o[1] << 16);
        op.y = (uint)o[2] | ((uint)o[3] << 16);
        *(uint2*)(gp + l) = op;
      }
    }
  }
}

// ---------------------------------------------------------------------------
// Kernel 3: transpose g[b][h][l] -> gt[b][l][h] (64x64 tiles, XOR-swizzled)
// ---------------------------------------------------------------------------
__global__ __launch_bounds__(256) void transpose_kernel(
    const ushort* __restrict__ g, ushort* __restrict__ gt) {
  __shared__ __align__(16) ushort Ts[64 * 64];
  const int l0 = blockIdx.x * 64, hh0 = blockIdx.y * 64, b = blockIdx.z;
  const int tid = threadIdx.x;
#pragma unroll
  for (int p = 0; p < 2; ++p) {
    const int hh = (tid >> 3) + 32 * p;
    const int c8 = tid & 7;
    const uint4 v = *(const uint4*)(g + (((size_t)(b * HDIM + hh0 + hh)) << 13)
                                    + l0 + c8 * 8);
    ((uint4*)Ts)[hh * 8 + (c8 ^ ((hh >> 3) & 7))] = v;
  }
  __syncthreads();
#pragma unroll
  for (int p = 0; p < 2; ++p) {
    const int lr = (tid >> 3) + 32 * p;
    const int o8 = tid & 7;
    U16 pk;
#pragma unroll
    for (int j = 0; j < 8; ++j) {
      const int hq = o8 * 8 + j;
      pk.e[j] = Ts[hq * 64 + (((lr >> 3) ^ o8) << 3) + (lr & 7)];
    }
    ((uint4*)(gt + ((size_t)b * LFULL + l0 + lr) * HDIM + hh0))[o8] = pk.u;
  }
}

// ---------------------------------------------------------------------------
// Kernel 4: W fp32 -> bf16
// ---------------------------------------------------------------------------
__global__ __launch_bounds__(256) void wcvt_kernel(const float* __restrict__ W,
                                                   ushort* __restrict__ Wb) {
  const int i = (blockIdx.x * 256 + threadIdx.x) * 8;
  const float4 v0 = *(const float4*)(W + i);
  const float4 v1 = *(const float4*)(W + i + 4);
  U16 pk;
  pk.e[0] = f2bf(v0.x); pk.e[1] = f2bf(v0.y);
  pk.e[2] = f2bf(v0.z); pk.e[3] = f2bf(v0.w);
  pk.e[4] = f2bf(v1.x); pk.e[5] = f2bf(v1.y);
  pk.e[6] = f2bf(v1.z); pk.e[7] = f2bf(v1.w);
  ((uint4*)Wb)[i >> 3] = pk.u;
}

// ---------------------------------------------------------------------------
// Kernel 5: out[b,o,l] = bo[o] + sum_h Wb[o,h]*gt[b,l,h]  (128x128 MFMA GEMM)
// ---------------------------------------------------------------------------
__global__ __launch_bounds__(256, 2) void outmm_kernel(
    const ushort* __restrict__ Wb, const ushort* __restrict__ gt,
    const float* __restrict__ bo, float* __restrict__ out) {
  __shared__ __align__(16) ushort As[128 * 32];
  __shared__ __align__(16) ushort Bs[128 * 32];
  const int tid = threadIdx.x;
  const int l0 = blockIdx.x * 128, o0 = blockIdx.y * 128, b = blockIdx.z;
  const int w = tid >> 6, lane = tid & 63;
  const int wm = w >> 1, wn = w & 1;
  const int col = lane & 15, q = lane >> 4;
  const int srow = lane >> 2, scol = (lane & 3) * 8;
  f32x4 acc[4][4];
#pragma unroll
  for (int m = 0; m < 4; ++m)
#pragma unroll
    for (int n = 0; n < 4; ++n) acc[m][n] = (f32x4){0.f, 0.f, 0.f, 0.f};
  const ushort* gb = gt + ((size_t)b * LFULL) * HDIM;
  for (int kt = 0; kt < 32; ++kt) {
    const int k0 = kt * 32;
    const int r0 = w * 32;
#pragma unroll
    for (int ii = 0; ii < 2; ++ii) {
      const int ra = r0 + ii * 16 + srow;
      gload16(Wb + (size_t)(o0 + ra) * HDIM + k0 + scol,
              As + (r0 + ii * 16) * 32);
      gload16(gb + (size_t)(l0 + ra) * HDIM + k0 + scol,
              Bs + (r0 + ii * 16) * 32);
    }
    __syncthreads();
    bf16x8 aa[4], bb[4];
#pragma unroll
    for (int m = 0; m < 4; ++m) {
      aa[m] = ((const bf16x8*)As)[(wm * 64 + m * 16 + col) * 4 + q];
      bb[m] = ((const bf16x8*)Bs)[(wn * 64 + m * 16 + col) * 4 + q];
    }
#pragma unroll
    for (int m = 0; m < 4; ++m)
#pragma unroll
      for (int n = 0; n < 4; ++n)
        acc[m][n] = __builtin_amdgcn_mfma_f32_16x16x32_bf16(aa[m], bb[n],
                                                            acc[m][n], 0, 0, 0);
    __syncthreads();
  }
#pragma unroll
  for (int m = 0; m < 4; ++m) {
    const int ob = o0 + wm * 64 + m * 16 + q * 4;
    const float4 bv = *(const float4*)(bo + ob);
    const float bva[4] = {bv.x, bv.y, bv.z, bv.w};
#pragma unroll
    for (int n = 0; n < 4; ++n) {
      const int l = l0 + wn * 64 + n * 16 + col;
      float* op = out + (((size_t)(b * HDIM + ob)) << 13) + l;
#pragma unroll
      for (int v = 0; v < 4; ++v) op[(size_t)v << 13] = acc[m][n][v] + bva[v];
    }
  }
}

// ---------------------------------------------------------------------------
extern "C" void kernel_launch(void* const* d_in, const int* in_sizes, int n_in,
                              void* d_out, int out_size, void* d_ws,
                              size_t ws_size, hipStream_t stream) {
  const float* u = (const float*)d_in[0];     // (4, 1024, 8192)
  const float* kern = (const float*)d_in[1];  // (8, 1, 1024, 64)
  const float* D = (const float*)d_in[2];     // (1, 1024)
  const float* W = (const float*)d_in[3];     // (1024, 1024)
  const float* bo = (const float*)d_in[4];    // (1024,)
  float* out = (float*)d_out;                 // (4, 1024, 8192)

  char* ws = (char*)d_ws;
  ushort* g = (ushort*)ws;                                 // [0, 64 MiB)
  ushort* gt = (ushort*)(ws + ((size_t)64 << 20));         // [64, 128 MiB)
  ushort* kbrev = (ushort*)(ws + ((size_t)128 << 20));     // 1024*8448*2 = 16.5 MiB
  ushort* Wb = (ushort*)(ws + ((size_t)128 << 20));        // reuses kbrev region

  k_synth_kernel<<<HDIM, 256, 0, stream>>>(kern, kbrev);
  conv_mfma_kernel<<<HDIM, 256, 0, stream>>>(u, kbrev, D, g);
  // kbrev dead from here; Wb overlays it.
  wcvt_kernel<<<512, 256, 0, stream>>>(W, Wb);
  transpose_kernel<<<dim3(128, 16, 4), 256, 0, stream>>>(g, gt);
  outmm_kernel<<<dim3(64, 8, 4), 256, 0, stream>>>(Wb, gt, bo, out);
}